// Round 6
// baseline (78.354 us; speedup 1.0000x reference)
//
#include <hip/hip_runtime.h>

#define NB 16
#define HH 1024
#define WW 1024
#define TW 128         // tile width  (32 col-groups * 4)
#define TH 64          // tile height (8 row-groups * 8)

#define EPS1 2e-4f     // edge-threshold confidence margin (f32 err bound ~4e-6)
#define EPS2 1e-4f     // final-threshold confidence margin (f32 err bound ~4e-6)

typedef float f32x4 __attribute__((ext_vector_type(4)));

// Cold exact-path: recompute one pixel in f64 straight from global memory
// (same math as the R1 kernel that scored absmax 0.0 vs the np/f64 reference).
__device__ __noinline__ float aes_exact_g(const float* __restrict__ m,
                                          int gy, int gx,
                                          float bsf, float esf, float fthr)
{
    const double bfd   = (double)bsf / 3.0;
    const double ethrd = 0.5 * (double)esf;
    const double fthrd = (double)fthr;
    const double w25d  = (double)(1.0f / 25.0f);

    double s25 = 0.0, s9 = 0.0;
    for (int dy = -2; dy <= 2; ++dy)
        for (int dx = -2; dx <= 2; ++dx) {
            int yy = gy + dy, xx = gx + dx;
            double v = 0.0;
            if ((unsigned)yy < (unsigned)HH && (unsigned)xx < (unsigned)WW)
                v = (double)m[(size_t)yy * WW + xx];
            s25 += v;
            if (dy >= -1 && dy <= 1 && dx >= -1 && dx <= 1) s9 += v;
        }
    double c      = (double)m[(size_t)gy * WW + gx];
    double edges  = fabs(9.0 * c - s9);
    double sbase  = s25 * w25d;
    double smooth = c * (1.0 - bfd) + sbase * bfd;
    double result = (edges > ethrd) ? smooth : c;
    return (result > fthrd) ? 1.0f : 0.0f;
}

__global__ __launch_bounds__(256)
void aes_kernel(const float* __restrict__ mask,
                const float* __restrict__ blur_strength,
                const float* __restrict__ edge_sensitivity,
                const float* __restrict__ final_threshold,
                float* __restrict__ out)
{
    const int b      = blockIdx.z;
    const int tile_x = blockIdx.x * TW;
    const int tile_y = blockIdx.y * TH;
    const float* m = mask + (size_t)b * (HH * WW);

    const float bsf    = blur_strength[b];
    const float esf    = edge_sensitivity[b];
    const float fthr   = final_threshold[b];
    const float ethr   = 0.5f * esf;          // exact in f32
    const float bff    = bsf / 3.0f;
    const float onembf = 1.0f - bff;
    const float w25f   = 1.0f / 25.0f;

    // thread -> 4 cols x 8 rows micro-tile, read straight from global
    const int tx = threadIdx.x & 31;          // col group
    const int ty = threadIdx.x >> 5;          // row group
    const int x0 = tile_x + 4 * tx;           // first output col (mult of 4)
    const int y0 = tile_y + 8 * ty;           // first output row

    const bool lok = (x0 > 0);                // left  float2 in-bounds?
    const bool rok = (x0 < WW - 4);           // right float2 in-bounds?

    // rolling ring over 5 input rows; [ring][col]
    float h5[5][4], h3[5][4], cc[5][4];

    // load 8 contiguous floats (global cols x0-2 .. x0+5) of row GY,
    // build rolling horizontal sums for the 4 output columns
#define LOADROW(GY, K)                                                      \
    {                                                                       \
        const int gy_ = (GY);                                               \
        const float* rp = m + (size_t)gy_ * WW + x0;                        \
        const bool rv = (unsigned)gy_ < (unsigned)HH;                       \
        float2 u0 = make_float2(0.f, 0.f);                                  \
        float4 u1 = make_float4(0.f, 0.f, 0.f, 0.f);                        \
        float2 u2 = make_float2(0.f, 0.f);                                  \
        if (rv) {                                                           \
            if (lok) u0 = *(const float2*)(rp - 2);   /* 8B aligned  */     \
            u1 = *(const float4*)rp;                  /* 16B aligned */     \
            if (rok) u2 = *(const float2*)(rp + 4);   /* 8B aligned  */     \
        }                                                                   \
        float a0 = u0.x, a1 = u0.y, a2 = u1.x, a3 = u1.y;                   \
        float a4 = u1.z, a5 = u1.w, a6 = u2.x, a7 = u2.y;                   \
        float s5 = ((a0 + a1) + (a2 + a3)) + a4;                            \
        h5[(K)][0] = s5; s5 = s5 - a0 + a5;                                 \
        h5[(K)][1] = s5; s5 = s5 - a1 + a6;                                 \
        h5[(K)][2] = s5; s5 = s5 - a2 + a7;                                 \
        h5[(K)][3] = s5;                                                    \
        float s3 = (a1 + a2) + a3;                                          \
        h3[(K)][0] = s3; s3 = s3 - a1 + a4;                                 \
        h3[(K)][1] = s3; s3 = s3 - a2 + a5;                                 \
        h3[(K)][2] = s3; s3 = s3 - a3 + a6;                                 \
        h3[(K)][3] = s3;                                                    \
        cc[(K)][0] = a2; cc[(K)][1] = a3; cc[(K)][2] = a4; cc[(K)][3] = a5; \
    }

    #pragma unroll
    for (int k = 0; k < 4; ++k)
        LOADROW(y0 - 2 + k, k)

    float* op = out + (size_t)b * (HH * WW) + (size_t)y0 * WW + x0;

    #pragma unroll
    for (int r = 0; r < 8; ++r) {
        LOADROW(y0 + 2 + r, (r + 4) % 5)
        const int i0 = r % 5, i1 = (r + 1) % 5, i2 = (r + 2) % 5;
        const int i3 = (r + 3) % 5, i4 = (r + 4) % 5;

        f32x4 ov;
        #pragma unroll
        for (int c = 0; c < 4; ++c) {
            float sum25  = ((h5[i0][c] + h5[i1][c]) + (h5[i2][c] + h5[i3][c])) + h5[i4][c];
            float s9     = h3[i1][c] + h3[i2][c] + h3[i3][c];
            float center = cc[i2][c];

            float edges  = fabsf(9.0f * center - s9);
            float sbase  = sum25 * w25f;
            float smooth = center * onembf + sbase * bff;

            bool isedge = edges > ethr;
            // no-edge branch compares EXACT center vs EXACT fthr -> always safe
            bool conf = (fabsf(edges - ethr) > EPS1) &&
                        (!isedge || (fabsf(smooth - fthr) > EPS2));
            float res = isedge ? smooth : center;
            float o   = (res > fthr) ? 1.0f : 0.0f;

            if (!conf)
                o = aes_exact_g(m, y0 + r, x0 + c, bsf, esf, fthr);

            ov[c] = o;          // c is compile-time after unroll
        }
        __builtin_nontemporal_store(ov, (f32x4*)(op + (size_t)r * WW));
    }
#undef LOADROW
}

extern "C" void kernel_launch(void* const* d_in, const int* in_sizes, int n_in,
                              void* d_out, int out_size, void* d_ws, size_t ws_size,
                              hipStream_t stream) {
    const float* mask = (const float*)d_in[0];
    const float* bs   = (const float*)d_in[1];
    const float* es   = (const float*)d_in[2];
    const float* ft   = (const float*)d_in[3];
    float* out = (float*)d_out;

    dim3 grid(WW / TW, HH / TH, NB);   // 8 x 16 x 16 = 2048 blocks
    aes_kernel<<<grid, 256, 0, stream>>>(mask, bs, es, ft, out);
}

// Round 7
// 36.488 us; speedup vs baseline: 2.1474x; 2.1474x over previous
//
#include <hip/hip_runtime.h>

#define NB 16
#define HH 1024
#define WW 1024
#define TW 128         // tile width  (output)
#define TH 32          // tile height (output)
#define LC 136         // staged cols: global x in [tile_x-4, tile_x+132)
#define LR 36          // staged rows: global y in [tile_y-2, tile_y+34)
#define N4 (LR * (LC / 4))   // float4 tiles to stage = 1224
#define NSTG 5               // ceil(N4 / 256)

#define EPS1 2e-4f     // edge-threshold confidence margin (f32 err bound ~4e-6)
#define EPS2 1e-4f     // final-threshold confidence margin (f32 err bound ~4e-6)

typedef float f32x4 __attribute__((ext_vector_type(4)));

// Cold exact-path: recompute one pixel in f64 from LDS (identical math to the
// R1 kernel that scored absmax 0.0 against the np/f64 reference).
__device__ __noinline__ float aes_exact(const float (*raw)[LC], int lr, int lc,
                                        float bsf, float esf, float fthr)
{
    const double bfd   = (double)bsf / 3.0;
    const double ethrd = 0.5 * (double)esf;
    const double fthrd = (double)fthr;
    const double w25d  = (double)(1.0f / 25.0f);

    double s25 = 0.0, s9 = 0.0;
    for (int dy = 0; dy < 5; ++dy)
        for (int dx = 0; dx < 5; ++dx) {
            double v = (double)raw[lr + dy][lc + dx];
            s25 += v;
            if (dy >= 1 && dy <= 3 && dx >= 1 && dx <= 3) s9 += v;
        }
    double c      = (double)raw[lr + 2][lc + 2];
    double edges  = fabs(9.0 * c - s9);
    double sbase  = s25 * w25d;
    double smooth = c * (1.0 - bfd) + sbase * bfd;
    double result = (edges > ethrd) ? smooth : c;
    return (result > fthrd) ? 1.0f : 0.0f;
}

__global__ __launch_bounds__(256)
void aes_kernel(const float* __restrict__ mask,
                const float* __restrict__ blur_strength,
                const float* __restrict__ edge_sensitivity,
                const float* __restrict__ final_threshold,
                float* __restrict__ out)
{
    __shared__ float raw[2][LR][LC];   // 39,168 B -> 4 blocks/CU, 16 waves/CU

    const int b      = blockIdx.z;
    const int tile_y = blockIdx.y * TH;
    const int tx0    = blockIdx.x * (2 * TW);   // this block: tiles tx0, tx0+TW
    const float* m = mask + (size_t)b * (HH * WW);

    const float bsf    = blur_strength[b];
    const float esf    = edge_sensitivity[b];
    const float fthr   = final_threshold[b];
    const float ethr   = 0.5f * esf;          // exact in f32
    const float bff    = bsf / 3.0f;
    const float onembf = 1.0f - bff;
    const float w25f   = 1.0f / 25.0f;

    // thread -> 4 cols x 4 rows micro-tile
    const int tx  = threadIdx.x & 31;
    const int ty  = threadIdx.x >> 5;
    const int lr0 = ty * 4;
    const int lc0 = 4 * tx + 2;

    f32x4 stg[NSTG];   // in-flight staging registers (static index via unroll)

    // ---- issue global loads for one tile into stg[] (no LDS, no waits) ----
#define STAGE_LOAD(TILE_X)                                                  \
    {                                                                       \
        _Pragma("unroll")                                                   \
        for (int k = 0; k < NSTG; ++k) {                                    \
            int i = (int)threadIdx.x + k * 256;                             \
            f32x4 v = {0.f, 0.f, 0.f, 0.f};                                 \
            if (i < N4) {                                                   \
                int row = i / (LC / 4);                                     \
                int c4  = i - row * (LC / 4);                               \
                int gy  = tile_y - 2 + row;                                 \
                int gx  = (TILE_X) - 4 + 4 * c4;    /* 16B aligned */       \
                if ((unsigned)gy < (unsigned)HH && (unsigned)gx < (unsigned)WW) \
                    v = *(const f32x4*)(m + (size_t)gy * WW + gx);          \
            }                                                               \
            stg[k] = v;                                                     \
        }                                                                   \
    }

    // ---- write stg[] into LDS buffer BUF (compiler inserts vmcnt waits) ----
#define STAGE_WRITE(BUF)                                                    \
    {                                                                       \
        _Pragma("unroll")                                                   \
        for (int k = 0; k < NSTG; ++k) {                                    \
            int i = (int)threadIdx.x + k * 256;                             \
            if (i < N4) {                                                   \
                int row = i / (LC / 4);                                     \
                int c4  = i - row * (LC / 4);                               \
                *(f32x4*)&raw[(BUF)][row][4 * c4] = stg[k];                 \
            }                                                               \
        }                                                                   \
    }

#define LOADROW(RB, ROWIDX, K)                                              \
    {                                                                       \
        const float* rp = &RB[(ROWIDX)][0];                                 \
        float2 u0 = *(const float2*)(rp + lc0);        /* 8B aligned  */    \
        float4 u1 = *(const float4*)(rp + lc0 + 2);    /* 16B aligned */    \
        float2 u2 = *(const float2*)(rp + lc0 + 6);    /* 8B aligned  */    \
        float a0 = u0.x, a1 = u0.y, a2 = u1.x, a3 = u1.y;                   \
        float a4 = u1.z, a5 = u1.w, a6 = u2.x, a7 = u2.y;                   \
        float s5 = ((a0 + a1) + (a2 + a3)) + a4;                            \
        h5[(K)][0] = s5; s5 = s5 - a0 + a5;                                 \
        h5[(K)][1] = s5; s5 = s5 - a1 + a6;                                 \
        h5[(K)][2] = s5; s5 = s5 - a2 + a7;                                 \
        h5[(K)][3] = s5;                                                    \
        float s3 = (a1 + a2) + a3;                                          \
        h3[(K)][0] = s3; s3 = s3 - a1 + a4;                                 \
        h3[(K)][1] = s3; s3 = s3 - a2 + a5;                                 \
        h3[(K)][2] = s3; s3 = s3 - a3 + a6;                                 \
        h3[(K)][3] = s3;                                                    \
        cc[(K)][0] = a2; cc[(K)][1] = a3; cc[(K)][2] = a4; cc[(K)][3] = a5; \
    }

    // ---- compute one 128x32 tile from LDS buffer BUF ----
#define COMPUTE(BUF, TILE_X)                                                \
    {                                                                       \
        const float (*rb)[LC] = raw[(BUF)];                                 \
        float h5[5][4], h3[5][4], cc[5][4];                                 \
        _Pragma("unroll")                                                   \
        for (int k = 0; k < 4; ++k)                                         \
            LOADROW(rb, lr0 + k, k)                                         \
        float* op = out + (size_t)b * (HH * WW)                             \
                        + (size_t)(tile_y + ty * 4) * WW + (TILE_X) + 4 * tx; \
        _Pragma("unroll")                                                   \
        for (int r = 0; r < 4; ++r) {                                       \
            LOADROW(rb, lr0 + r + 4, (r + 4) % 5)                           \
            const int i0 = r % 5, i1 = (r + 1) % 5, i2 = (r + 2) % 5;       \
            const int i3 = (r + 3) % 5, i4 = (r + 4) % 5;                   \
            f32x4 ov;                                                       \
            _Pragma("unroll")                                               \
            for (int c = 0; c < 4; ++c) {                                   \
                float sum25  = ((h5[i0][c] + h5[i1][c])                     \
                              + (h5[i2][c] + h5[i3][c])) + h5[i4][c];       \
                float s9     = h3[i1][c] + h3[i2][c] + h3[i3][c];           \
                float center = cc[i2][c];                                   \
                float edges  = fabsf(9.0f * center - s9);                   \
                float sbase  = sum25 * w25f;                                \
                float smooth = center * onembf + sbase * bff;               \
                bool isedge = edges > ethr;                                 \
                bool conf = (fabsf(edges - ethr) > EPS1) &&                 \
                            (!isedge || (fabsf(smooth - fthr) > EPS2));     \
                float res = isedge ? smooth : center;                       \
                float o   = (res > fthr) ? 1.0f : 0.0f;                     \
                if (!conf)                                                  \
                    o = aes_exact(rb, lr0 + r, lc0 + c, bsf, esf, fthr);    \
                ov[c] = o;                                                  \
            }                                                               \
            __builtin_nontemporal_store(ov, (f32x4*)(op + (size_t)r * WW)); \
        }                                                                   \
    }

    // ---------------- pipeline: 2 tiles, double-buffered LDS --------------
    STAGE_LOAD(tx0)          // tile 0 -> regs
    STAGE_WRITE(0)           // regs -> LDS[0]   (vmcnt wait auto-inserted)
    __syncthreads();

    STAGE_LOAD(tx0 + TW)     // tile 1 loads fly under tile 0 compute
    COMPUTE(0, tx0)
    STAGE_WRITE(1)           // wait tile-1 loads, write LDS[1]
    __syncthreads();

    COMPUTE(1, tx0 + TW)

#undef STAGE_LOAD
#undef STAGE_WRITE
#undef LOADROW
#undef COMPUTE
}

extern "C" void kernel_launch(void* const* d_in, const int* in_sizes, int n_in,
                              void* d_out, int out_size, void* d_ws, size_t ws_size,
                              hipStream_t stream) {
    const float* mask = (const float*)d_in[0];
    const float* bs   = (const float*)d_in[1];
    const float* es   = (const float*)d_in[2];
    const float* ft   = (const float*)d_in[3];
    float* out = (float*)d_out;

    dim3 grid(WW / (2 * TW), HH / TH, NB);   // 4 x 32 x 16 = 2048 blocks
    aes_kernel<<<grid, 256, 0, stream>>>(mask, bs, es, ft, out);
}